// Round 1
// baseline (2990.010 us; speedup 1.0000x reference)
//
#include <hip/hip_runtime.h>
#include <math.h>

#define HW   1600
#define C0   64
#define K0   2048
#define C1   256
#define K1   512
#define C2E  (-14.42695040888963f)   // -log2(e)/T, T=0.1

static const size_t OFF_X3  = 0;
static const size_t OFF_QX0 = 13107200;
static const size_t OFF_QX3 = 16384000;
static const size_t OFF_A0  = 29491200;
static const size_t OFF_A3  = 134348800;
static const size_t OFF_D0  = 160563200;
static const size_t OFF_D3  = 265420800;

// ---------------- kernel 0: codebook squared norms ----------------
__global__ __launch_bounds__(256) void k_esq(const float* __restrict__ vq0,
                                             const float* __restrict__ vq1,
                                             float* __restrict__ esq) {
    int r = blockIdx.x * 256 + threadIdx.x;
    if (r < K0) {
        float s = 0.f;
        for (int c = 0; c < C0; c++) { float v = vq0[r * C0 + c]; s += v * v; }
        esq[r] = s;
    } else if (r < K0 + K1) {
        int rr = r - K0;
        float s = 0.f;
        for (int c = 0; c < C1; c++) { float v = vq1[rr * C1 + c]; s += v * v; }
        esq[K0 + rr] = s;
    }
}

// ---------------- kernel A: stage-0 distances + online softmax stats ----------------
// 64 rows/block (grid 800). esT staged with 16B-group XOR swizzle -> conflict-free writes.
// Per-thread online (m,s) in base-2; single cross-lane reduce at kernel end.
__global__ __launch_bounds__(256) void k_dist0(const float* __restrict__ x0,
                                               const float* __restrict__ cb,
                                               const float* __restrict__ esq,
                                               float* __restrict__ d0,
                                               float* __restrict__ stats) {
    __shared__ __align__(16) float xs[64][68];
    __shared__ __align__(16) float esT[64][132];
    __shared__ float part[64][4];
    __shared__ float xsq[64];

    const int t = threadIdx.x;
    const int n0 = blockIdx.x * 64;
    const int b = n0 / HW, hw0 = n0 % HW;

    for (int i = t; i < 64 * 64; i += 256) {
        int c = i >> 6, r = i & 63;
        xs[r][c] = x0[(size_t)(b * C0 + c) * HW + hw0 + r];
    }
    __syncthreads();
    {
        int r = t & 63, seg = t >> 6;
        float s = 0.f;
        #pragma unroll
        for (int j = 0; j < 16; j++) { float v = xs[r][seg * 16 + j]; s += v * v; }
        part[r][seg] = s;
    }
    __syncthreads();
    if (t < 64) xsq[t] = part[t][0] + part[t][1] + part[t][2] + part[t][3];
    __syncthreads();

    const int rg = t >> 5;   // rows rg*8..+7
    const int kg = t & 31;   // ks kg*4..+3 within chunk

    float m2r[8], sr[8];
    #pragma unroll
    for (int i = 0; i < 8; i++) { m2r[i] = -3.0e38f; sr[i] = 0.f; }

    for (int k0 = 0; k0 < K0; k0 += 128) {
        // stage codebook transposed, swizzled: element (kk,c) at esT[c][((kk>>2)^((c>>2)&7))*4 + (kk&3)]
        for (int i = t; i < 2048; i += 256) {
            int c4 = i & 15, kk = i >> 4;
            float4 e = *(const float4*)&cb[(size_t)(k0 + kk) * C0 + c4 * 4];
            int col = (((kk >> 2) ^ (c4 & 7)) << 2) | (kk & 3);
            esT[c4 * 4 + 0][col] = e.x;
            esT[c4 * 4 + 1][col] = e.y;
            esT[c4 * 4 + 2][col] = e.z;
            esT[c4 * 4 + 3][col] = e.w;
        }
        __syncthreads();

        float acc[8][4];
        #pragma unroll
        for (int i = 0; i < 8; i++)
            #pragma unroll
            for (int j = 0; j < 4; j++) acc[i][j] = 0.f;

        #pragma unroll 2
        for (int c = 0; c < 64; c += 4) {
            int kgf = ((kg ^ ((c >> 2) & 7)) << 2);
            float4 e0 = *(const float4*)&esT[c + 0][kgf];
            float4 e1 = *(const float4*)&esT[c + 1][kgf];
            float4 e2 = *(const float4*)&esT[c + 2][kgf];
            float4 e3 = *(const float4*)&esT[c + 3][kgf];
            #pragma unroll
            for (int i = 0; i < 8; i++) {
                float4 xt = *(const float4*)&xs[rg * 8 + i][c];
                acc[i][0] += xt.x * e0.x + xt.y * e1.x + xt.z * e2.x + xt.w * e3.x;
                acc[i][1] += xt.x * e0.y + xt.y * e1.y + xt.z * e2.y + xt.w * e3.y;
                acc[i][2] += xt.x * e0.z + xt.y * e1.z + xt.z * e2.z + xt.w * e3.z;
                acc[i][3] += xt.x * e0.w + xt.y * e1.w + xt.z * e2.w + xt.w * e3.w;
            }
        }

        float4 eq = *(const float4*)&esq[k0 + kg * 4];
        #pragma unroll
        for (int i = 0; i < 8; i++) {
            int r = rg * 8 + i;
            float xq = xsq[r];
            float d0v = (xq + eq.x) - 2.f * acc[i][0];
            float d1v = (xq + eq.y) - 2.f * acc[i][1];
            float d2v = (xq + eq.z) - 2.f * acc[i][2];
            float d3v = (xq + eq.w) - 2.f * acc[i][3];
            float4 st; st.x = d0v; st.y = d1v; st.z = d2v; st.w = d3v;
            *(float4*)&d0[(size_t)(n0 + r) * K0 + k0 + kg * 4] = st;
            float p0 = C2E * d0v, p1 = C2E * d1v, p2 = C2E * d2v, p3 = C2E * d3v;
            float mm = fmaxf(fmaxf(p0, p1), fmaxf(p2, p3));
            float Mn = fmaxf(m2r[i], mm);
            float ss = __builtin_amdgcn_exp2f(p0 - Mn) + __builtin_amdgcn_exp2f(p1 - Mn)
                     + __builtin_amdgcn_exp2f(p2 - Mn) + __builtin_amdgcn_exp2f(p3 - Mn);
            sr[i] = sr[i] * __builtin_amdgcn_exp2f(m2r[i] - Mn) + ss;
            m2r[i] = Mn;
        }
        __syncthreads();
    }

    // single cross-lane reduce over the 32 kg lanes
    #pragma unroll
    for (int off = 1; off < 32; off <<= 1) {
        #pragma unroll
        for (int i = 0; i < 8; i++) {
            float m2 = __shfl_xor(m2r[i], off, 64);
            float s2 = __shfl_xor(sr[i], off, 64);
            float Mn = fmaxf(m2r[i], m2);
            sr[i] = sr[i] * __builtin_amdgcn_exp2f(m2r[i] - Mn)
                  + s2 * __builtin_amdgcn_exp2f(m2 - Mn);
            m2r[i] = Mn;
        }
    }
    if (kg == 0) {
        #pragma unroll
        for (int i = 0; i < 8; i++) {
            int r = rg * 8 + i;
            stats[(size_t)(n0 + r) * 2]     = m2r[i];
            stats[(size_t)(n0 + r) * 2 + 1] = sr[i];
        }
    }
}

// ---------------- kernel B: stage-0 prob -> a0, q_feat -> qx0 ----------------
// 64 rows/block (grid 800), register prefetch of next d0 chunk, 256B a0 stores.
__global__ __launch_bounds__(256) void k_prob0(const float* __restrict__ x0,
                                               const float* __restrict__ cb,
                                               const float* __restrict__ stats,
                                               const int* __restrict__ iter,
                                               const float* __restrict__ d0,
                                               float* __restrict__ out) {
    __shared__ __align__(16) float es[128][68];   // [kk][c]
    __shared__ float ptT[128][66];                // [kk][r]
    __shared__ float rowM[64], rowIS[64];

    const int t = threadIdx.x;
    const int n0 = blockIdx.x * 64;
    const int b = n0 / HW, hw0 = n0 % HW;

    if (t < 64) {
        rowM[t]  = stats[(size_t)(n0 + t) * 2];
        rowIS[t] = 1.f / stats[(size_t)(n0 + t) * 2 + 1];
    }
    __syncthreads();

    const int r1 = t >> 2;          // 0..63
    const int ks1 = (t & 3) * 32;   // 32-k slice
    const int rq = t & 63;
    const int cg = t >> 6;          // 0..3 -> 16 channels each
    const float Mr1 = rowM[r1], IS1 = rowIS[r1];

    float qf[16];
    #pragma unroll
    for (int q = 0; q < 16; q++) qf[q] = 0.f;

    float* a0 = out + OFF_A0;

    float4 dpre[8];
    {
        const float* dr = &d0[(size_t)(n0 + r1) * K0 + ks1];
        #pragma unroll
        for (int q = 0; q < 8; q++) dpre[q] = *(const float4*)&dr[q * 4];
    }

    for (int k0 = 0; k0 < K0; k0 += 128) {
        for (int i = t; i < 2048; i += 256) {
            int c4 = i & 15, kk = i >> 4;
            *(float4*)&es[kk][c4 * 4] =
                *(const float4*)&cb[(size_t)(k0 + kk) * C0 + c4 * 4];
        }
        #pragma unroll
        for (int q = 0; q < 8; q++) {
            float4 dv = dpre[q];
            int kb = ks1 + q * 4;
            ptT[kb + 0][r1] = __builtin_amdgcn_exp2f(C2E * dv.x - Mr1) * IS1;
            ptT[kb + 1][r1] = __builtin_amdgcn_exp2f(C2E * dv.y - Mr1) * IS1;
            ptT[kb + 2][r1] = __builtin_amdgcn_exp2f(C2E * dv.z - Mr1) * IS1;
            ptT[kb + 3][r1] = __builtin_amdgcn_exp2f(C2E * dv.w - Mr1) * IS1;
        }
        if (k0 + 128 < K0) {   // prefetch next chunk; latency hides under a0+qf phases
            const float* dr = &d0[(size_t)(n0 + r1) * K0 + k0 + 128 + ks1];
            #pragma unroll
            for (int q = 0; q < 8; q++) dpre[q] = *(const float4*)&dr[q * 4];
        }
        __syncthreads();
        #pragma unroll
        for (int jj = 0; jj < 32; jj++) {
            int pos = jj * 256 + t;
            int kk = pos >> 6, r = pos & 63;
            a0[(size_t)(b * K0 + k0 + kk) * HW + hw0 + r] = ptT[kk][r];
        }
        #pragma unroll 8
        for (int kk = 0; kk < 128; kk++) {
            float p = ptT[kk][rq];
            float4 e0 = *(const float4*)&es[kk][cg * 16];
            float4 e1 = *(const float4*)&es[kk][cg * 16 + 4];
            float4 e2 = *(const float4*)&es[kk][cg * 16 + 8];
            float4 e3 = *(const float4*)&es[kk][cg * 16 + 12];
            qf[0]  += p * e0.x; qf[1]  += p * e0.y; qf[2]  += p * e0.z; qf[3]  += p * e0.w;
            qf[4]  += p * e1.x; qf[5]  += p * e1.y; qf[6]  += p * e1.z; qf[7]  += p * e1.w;
            qf[8]  += p * e2.x; qf[9]  += p * e2.y; qf[10] += p * e2.z; qf[11] += p * e2.w;
            qf[12] += p * e3.x; qf[13] += p * e3.y; qf[14] += p * e3.z; qf[15] += p * e3.w;
        }
        __syncthreads();
    }
    float gate = fmaxf((10000.f - (float)(*iter)) / 10000.f, 0.f);
    float om = 1.f - gate;
    #pragma unroll
    for (int q = 0; q < 16; q++) {
        int c = cg * 16 + q;
        size_t idx = (size_t)(b * C0 + c) * HW + hw0 + rq;
        out[OFF_QX0 + idx] = gate * x0[idx] + om * qf[q];
    }
}

// ---------------- kernel C: fused head (two 1x1 convs + relu) ----------------
__global__ __launch_bounds__(256) void k_head(const float* __restrict__ w1,
                                              const float* __restrict__ b1,
                                              const float* __restrict__ w2,
                                              const float* __restrict__ b2,
                                              float* __restrict__ out) {
    __shared__ __align__(16) float xin[32][64];
    __shared__ __align__(16) float y1s[32][256];
    __shared__ __align__(16) float wst[64][68];

    const int t = threadIdx.x;
    const int n0 = blockIdx.x * 32;
    const int b = n0 / HW, hw0 = n0 % HW;
    const float* qx0 = out + OFF_QX0;
    float* x3 = out + OFF_X3;

    for (int i = t; i < 32 * 64; i += 256) {
        int c = i >> 5, r = i & 31;
        xin[r][c] = qx0[(size_t)(b * C0 + c) * HW + hw0 + r];
    }
    __syncthreads();

    const int rg = t >> 5;
    const int og = t & 31;

    for (int op = 0; op < 4; op++) {
        int ob = op * 64;
        for (int i = t; i < 64 * 64; i += 256) {
            int c = i & 63, o = i >> 6;
            wst[c][o] = w1[(size_t)(ob + o) * C0 + c];
        }
        __syncthreads();
        float2 bb = *(const float2*)&b1[ob + og * 2];
        float acc[4][2];
        #pragma unroll
        for (int i = 0; i < 4; i++) { acc[i][0] = bb.x; acc[i][1] = bb.y; }
        #pragma unroll 2
        for (int c = 0; c < 64; c += 4) {
            float xv[4][4];
            #pragma unroll
            for (int i = 0; i < 4; i++) {
                float4 xt = *(const float4*)&xin[rg * 4 + i][c];
                xv[i][0] = xt.x; xv[i][1] = xt.y; xv[i][2] = xt.z; xv[i][3] = xt.w;
            }
            #pragma unroll
            for (int q = 0; q < 4; q++) {
                float2 wv = *(const float2*)&wst[c + q][og * 2];
                #pragma unroll
                for (int i = 0; i < 4; i++) {
                    acc[i][0] += xv[i][q] * wv.x;
                    acc[i][1] += xv[i][q] * wv.y;
                }
            }
        }
        #pragma unroll
        for (int i = 0; i < 4; i++) {
            float2 st;
            st.x = fmaxf(acc[i][0], 0.f);
            st.y = fmaxf(acc[i][1], 0.f);
            *(float2*)&y1s[rg * 4 + i][ob + og * 2] = st;
        }
        __syncthreads();
    }

    for (int p = 0; p < 4; p++) {
        int ob = p * 64;
        float2 bb = *(const float2*)&b2[ob + og * 2];
        float acc[4][2];
        #pragma unroll
        for (int i = 0; i < 4; i++) { acc[i][0] = bb.x; acc[i][1] = bb.y; }
        for (int cc0 = 0; cc0 < 256; cc0 += 64) {
            for (int i = t; i < 64 * 64; i += 256) {
                int c = i & 63, o = i >> 6;
                wst[c][o] = w2[(size_t)(ob + o) * C1 + cc0 + c];
            }
            __syncthreads();
            #pragma unroll 2
            for (int c = 0; c < 64; c += 4) {
                float yv[4][4];
                #pragma unroll
                for (int i = 0; i < 4; i++) {
                    float4 yt = *(const float4*)&y1s[rg * 4 + i][cc0 + c];
                    yv[i][0] = yt.x; yv[i][1] = yt.y; yv[i][2] = yt.z; yv[i][3] = yt.w;
                }
                #pragma unroll
                for (int q = 0; q < 4; q++) {
                    float2 wv = *(const float2*)&wst[c + q][og * 2];
                    #pragma unroll
                    for (int i = 0; i < 4; i++) {
                        acc[i][0] += yv[i][q] * wv.x;
                        acc[i][1] += yv[i][q] * wv.y;
                    }
                }
            }
            __syncthreads();
        }
        #pragma unroll
        for (int i = 0; i < 4; i++)
            *(float2*)&wst[0][0 + (size_t)(rg * 4 + i) * 68 + og * 2] =
                make_float2(acc[i][0], acc[i][1]);
        __syncthreads();
        for (int i = t; i < 32 * 64; i += 256) {
            int o = i >> 5, r = i & 31;
            x3[(size_t)(b * C1 + ob + o) * HW + hw0 + r] = wst[0][(size_t)r * 68 + o];
        }
        __syncthreads();
    }
}

// ---------------- kernel D: stage-1 distances + stats ----------------
// x3 tile staged ONCE (was restaged 16x); conflict-free stride-37 esT; per-thread online stats.
__global__ __launch_bounds__(256) void k_dist1(const float* __restrict__ cb,
                                               const float* __restrict__ esq,
                                               const float* __restrict__ x3,
                                               float* __restrict__ d3,
                                               float* __restrict__ stats) {
    __shared__ __align__(16) float xs[32][260];
    __shared__ float esT[256][37];   // [c][kk], odd-ish stride: conflict-free writes & reads
    __shared__ float part[32][8];
    __shared__ float xsq[32];

    const int t = threadIdx.x;
    const int n0 = blockIdx.x * 32;
    const int b = n0 / HW, hw0 = n0 % HW;

    for (int i = t; i < 32 * 256; i += 256) {
        int ci = i >> 5, r = i & 31;
        xs[r][ci] = x3[(size_t)(b * C1 + ci) * HW + hw0 + r];
    }
    __syncthreads();
    {
        int r = t & 31, seg = t >> 5;
        float s = 0.f;
        #pragma unroll
        for (int j = 0; j < 32; j++) { float v = xs[r][seg * 32 + j]; s += v * v; }
        part[r][seg] = s;
    }
    __syncthreads();
    if (t < 32) {
        float s = 0.f;
        #pragma unroll
        for (int j = 0; j < 8; j++) s += part[t][j];
        xsq[t] = s;
    }
    __syncthreads();

    const int rg = t >> 5;
    const int kg = t & 31;

    float m2r[4], sr[4];
    #pragma unroll
    for (int i = 0; i < 4; i++) { m2r[i] = -3.0e38f; sr[i] = 0.f; }

    for (int k0 = 0; k0 < K1; k0 += 32) {
        for (int i = t; i < 32 * 256; i += 256) {
            int c = i & 255, kk = i >> 8;
            esT[c][kk] = cb[(size_t)(k0 + kk) * C1 + c];
        }
        __syncthreads();

        float acc[4] = {0.f, 0.f, 0.f, 0.f};
        #pragma unroll 2
        for (int c = 0; c < 256; c += 4) {
            float e0 = esT[c + 0][kg];
            float e1 = esT[c + 1][kg];
            float e2 = esT[c + 2][kg];
            float e3 = esT[c + 3][kg];
            #pragma unroll
            for (int i = 0; i < 4; i++) {
                float4 xt = *(const float4*)&xs[rg * 4 + i][c];
                acc[i] += xt.x * e0 + xt.y * e1 + xt.z * e2 + xt.w * e3;
            }
        }
        float eqv = esq[k0 + kg];
        #pragma unroll
        for (int i = 0; i < 4; i++) {
            int r = rg * 4 + i;
            float dv = (xsq[r] + eqv) - 2.f * acc[i];
            d3[(size_t)(n0 + r) * K1 + k0 + kg] = dv;
            float p = C2E * dv;
            float Mn = fmaxf(m2r[i], p);
            sr[i] = sr[i] * __builtin_amdgcn_exp2f(m2r[i] - Mn)
                  + __builtin_amdgcn_exp2f(p - Mn);
            m2r[i] = Mn;
        }
        __syncthreads();
    }

    #pragma unroll
    for (int off = 1; off < 32; off <<= 1) {
        #pragma unroll
        for (int i = 0; i < 4; i++) {
            float m2 = __shfl_xor(m2r[i], off, 64);
            float s2 = __shfl_xor(sr[i], off, 64);
            float Mn = fmaxf(m2r[i], m2);
            sr[i] = sr[i] * __builtin_amdgcn_exp2f(m2r[i] - Mn)
                  + s2 * __builtin_amdgcn_exp2f(m2 - Mn);
            m2r[i] = Mn;
        }
    }
    if (kg == 0) {
        #pragma unroll
        for (int i = 0; i < 4; i++) {
            int r = rg * 4 + i;
            stats[(size_t)(n0 + r) * 2]     = m2r[i];
            stats[(size_t)(n0 + r) * 2 + 1] = sr[i];
        }
    }
}

// ---------------- kernel E: stage-1 prob -> a3, q_feat -> qx3 ----------------
__global__ __launch_bounds__(256) void k_prob1(const float* __restrict__ cb,
                                               const float* __restrict__ stats,
                                               const int* __restrict__ iter,
                                               const float* __restrict__ d3,
                                               float* __restrict__ out) {
    __shared__ __align__(16) float es[64][132];   // [kk][c-half]
    __shared__ float ptT[64][33];
    __shared__ float rowM[32], rowIS[32];

    const int t = threadIdx.x;
    const int n0 = blockIdx.x * 32;
    const int b = n0 / HW, hw0 = n0 % HW;

    if (t < 32) {
        rowM[t]  = stats[(size_t)(n0 + t) * 2];
        rowIS[t] = 1.f / stats[(size_t)(n0 + t) * 2 + 1];
    }
    __syncthreads();

    const int r1 = t >> 3;
    const int ks1 = (t & 7) * 8;
    const int rq = t & 31;
    const int cg = t >> 5;
    const float Mr1 = rowM[r1], IS1 = rowIS[r1];

    float qf0[16], qf1[16];
    #pragma unroll
    for (int q = 0; q < 16; q++) { qf0[q] = 0.f; qf1[q] = 0.f; }

    const float* x3 = out + OFF_X3;
    float* a3 = out + OFF_A3;

    float4 dpre0, dpre1;
    {
        const float* dr = &d3[(size_t)(n0 + r1) * K1 + ks1];
        dpre0 = *(const float4*)&dr[0];
        dpre1 = *(const float4*)&dr[4];
    }

    for (int k0 = 0; k0 < K1; k0 += 64) {
        {
            float4 v0 = dpre0, v1 = dpre1;
            ptT[ks1 + 0][r1] = __builtin_amdgcn_exp2f(C2E * v0.x - Mr1) * IS1;
            ptT[ks1 + 1][r1] = __builtin_amdgcn_exp2f(C2E * v0.y - Mr1) * IS1;
            ptT[ks1 + 2][r1] = __builtin_amdgcn_exp2f(C2E * v0.z - Mr1) * IS1;
            ptT[ks1 + 3][r1] = __builtin_amdgcn_exp2f(C2E * v0.w - Mr1) * IS1;
            ptT[ks1 + 4][r1] = __builtin_amdgcn_exp2f(C2E * v1.x - Mr1) * IS1;
            ptT[ks1 + 5][r1] = __builtin_amdgcn_exp2f(C2E * v1.y - Mr1) * IS1;
            ptT[ks1 + 6][r1] = __builtin_amdgcn_exp2f(C2E * v1.z - Mr1) * IS1;
            ptT[ks1 + 7][r1] = __builtin_amdgcn_exp2f(C2E * v1.w - Mr1) * IS1;
        }
        if (k0 + 64 < K1) {
            const float* dr = &d3[(size_t)(n0 + r1) * K1 + k0 + 64 + ks1];
            dpre0 = *(const float4*)&dr[0];
            dpre1 = *(const float4*)&dr[4];
        }
        for (int i = t; i < 2048; i += 256) {     // es half0 (c 0..127)
            int c4 = i & 31, kk = i >> 5;
            *(float4*)&es[kk][c4 * 4] =
                *(const float4*)&cb[(size_t)(k0 + kk) * C1 + c4 * 4];
        }
        __syncthreads();
        #pragma unroll
        for (int jj = 0; jj < 8; jj++) {
            int pos = jj * 256 + t;
            int kk = pos >> 5, r = pos & 31;
            a3[(size_t)(b * K1 + k0 + kk) * HW + hw0 + r] = ptT[kk][r];
        }
        #pragma unroll 4
        for (int kk = 0; kk < 64; kk++) {
            float p = ptT[kk][rq];
            #pragma unroll
            for (int q = 0; q < 4; q++) {
                float4 e = *(const float4*)&es[kk][cg * 16 + q * 4];
                qf0[q * 4 + 0] += p * e.x;
                qf0[q * 4 + 1] += p * e.y;
                qf0[q * 4 + 2] += p * e.z;
                qf0[q * 4 + 3] += p * e.w;
            }
        }
        __syncthreads();
        for (int i = t; i < 2048; i += 256) {     // es half1 (c 128..255)
            int c4 = i & 31, kk = i >> 5;
            *(float4*)&es[kk][c4 * 4] =
                *(const float4*)&cb[(size_t)(k0 + kk) * C1 + 128 + c4 * 4];
        }
        __syncthreads();
        #pragma unroll 4
        for (int kk = 0; kk < 64; kk++) {
            float p = ptT[kk][rq];
            #pragma unroll
            for (int q = 0; q < 4; q++) {
                float4 e = *(const float4*)&es[kk][cg * 16 + q * 4];
                qf1[q * 4 + 0] += p * e.x;
                qf1[q * 4 + 1] += p * e.y;
                qf1[q * 4 + 2] += p * e.z;
                qf1[q * 4 + 3] += p * e.w;
            }
        }
        __syncthreads();
    }
    float gate = fmaxf((10000.f - (float)(*iter)) / 10000.f, 0.f);
    float om = 1.f - gate;
    #pragma unroll
    for (int q = 0; q < 16; q++) {
        int c = cg * 16 + q;
        size_t idx = (size_t)(b * C1 + c) * HW + hw0 + rq;
        out[OFF_QX3 + idx] = gate * x3[idx] + om * qf0[q];
    }
    #pragma unroll
    for (int q = 0; q < 16; q++) {
        int c = 128 + cg * 16 + q;
        size_t idx = (size_t)(b * C1 + c) * HW + hw0 + rq;
        out[OFF_QX3 + idx] = gate * x3[idx] + om * qf1[q];
    }
}

extern "C" void kernel_launch(void* const* d_in, const int* in_sizes, int n_in,
                              void* d_out, int out_size, void* d_ws, size_t ws_size,
                              hipStream_t stream) {
    (void)in_sizes; (void)n_in; (void)out_size; (void)ws_size;
    const float* x0  = (const float*)d_in[0];
    const float* vq0 = (const float*)d_in[1];
    const float* vq1 = (const float*)d_in[2];
    const float* w1  = (const float*)d_in[3];
    const float* b1  = (const float*)d_in[4];
    const float* w2  = (const float*)d_in[5];
    const float* b2  = (const float*)d_in[6];
    const int*   it  = (const int*)d_in[7];
    float* out = (float*)d_out;
    float* ws  = (float*)d_ws;
    float* esq0   = ws;                        // 2048
    float* esq1   = ws + 2048;                 // 512
    float* stats0 = ws + 2560;                 // 2*51200
    float* stats1 = ws + 2560 + 2 * 51200;     // 2*51200

    hipLaunchKernelGGL(k_esq,   dim3(10),   dim3(256), 0, stream, vq0, vq1, ws);
    hipLaunchKernelGGL(k_dist0, dim3(800),  dim3(256), 0, stream, x0, vq0, esq0,
                       out + OFF_D0, stats0);
    hipLaunchKernelGGL(k_prob0, dim3(800),  dim3(256), 0, stream, x0, vq0, stats0, it,
                       out + OFF_D0, out);
    hipLaunchKernelGGL(k_head,  dim3(1600), dim3(256), 0, stream, w1, b1, w2, b2, out);
    hipLaunchKernelGGL(k_dist1, dim3(1600), dim3(256), 0, stream, vq1, esq1,
                       out + OFF_X3, out + OFF_D3, stats1);
    hipLaunchKernelGGL(k_prob1, dim3(1600), dim3(256), 0, stream, vq1, stats1, it,
                       out + OFF_D3, out);
}

// Round 2
// 2591.446 us; speedup vs baseline: 1.1538x; 1.1538x over previous
//
#include <hip/hip_runtime.h>
#include <math.h>

#define HW   1600
#define C0   64
#define K0   2048
#define C1   256
#define K1   512
#define C2E  (-14.42695040888963f)   // -log2(e)/T, T=0.1

static const size_t OFF_X3  = 0;
static const size_t OFF_QX0 = 13107200;
static const size_t OFF_QX3 = 16384000;
static const size_t OFF_A0  = 29491200;
static const size_t OFF_A3  = 134348800;
static const size_t OFF_D0  = 160563200;
static const size_t OFF_D3  = 265420800;

// ---------------- kernel 0: codebook squared norms ----------------
__global__ __launch_bounds__(256) void k_esq(const float* __restrict__ vq0,
                                             const float* __restrict__ vq1,
                                             float* __restrict__ esq) {
    int r = blockIdx.x * 256 + threadIdx.x;
    if (r < K0) {
        float s = 0.f;
        for (int c = 0; c < C0; c++) { float v = vq0[r * C0 + c]; s += v * v; }
        esq[r] = s;
    } else if (r < K0 + K1) {
        int rr = r - K0;
        float s = 0.f;
        for (int c = 0; c < C1; c++) { float v = vq1[rr * C1 + c]; s += v * v; }
        esq[K0 + rr] = s;
    }
}

// ---------------- kernel A: stage-0 distances + online softmax stats ----------------
// 32-row tiles (grid 1600, 3 blocks/CU). Swizzled esT staging (float4 global loads,
// ~conflict-free LDS writes). Per-thread online (m,s) in base-2; ONE reduce at end.
__global__ __launch_bounds__(256) void k_dist0(const float* __restrict__ x0,
                                               const float* __restrict__ cb,
                                               const float* __restrict__ esq,
                                               float* __restrict__ d0,
                                               float* __restrict__ stats) {
    __shared__ __align__(16) float xs[32][68];
    __shared__ __align__(16) float esT[64][132];
    __shared__ float part[32][8];
    __shared__ float xsq[32];

    const int t = threadIdx.x;
    const int n0 = blockIdx.x * 32;
    const int b = n0 / HW, hw0 = n0 % HW;

    for (int i = t; i < 32 * 64; i += 256) {
        int c = i >> 5, r = i & 31;
        xs[r][c] = x0[(size_t)(b * C0 + c) * HW + hw0 + r];
    }
    __syncthreads();
    {
        int r = t & 31, seg = t >> 5;
        float s = 0.f;
        #pragma unroll
        for (int j = 0; j < 8; j++) { float v = xs[r][seg * 8 + j]; s += v * v; }
        part[r][seg] = s;
    }
    __syncthreads();
    if (t < 32) {
        float s = 0.f;
        #pragma unroll
        for (int j = 0; j < 8; j++) s += part[t][j];
        xsq[t] = s;
    }
    __syncthreads();

    const int rg = t >> 5;   // rows rg*4..+3
    const int kg = t & 31;   // ks kg*4..+3 within chunk

    float m2r[4], sr[4];
    #pragma unroll
    for (int i = 0; i < 4; i++) { m2r[i] = -3.0e38f; sr[i] = 0.f; }

    for (int k0 = 0; k0 < K0; k0 += 128) {
        // element (kk,c) stored at esT[c][((kk>>2)^((c>>2)&7))*4 + (kk&3)]
        for (int i = t; i < 2048; i += 256) {
            int c4 = i & 15, kk = i >> 4;
            float4 e = *(const float4*)&cb[(size_t)(k0 + kk) * C0 + c4 * 4];
            int col = (((kk >> 2) ^ (c4 & 7)) << 2) | (kk & 3);
            esT[c4 * 4 + 0][col] = e.x;
            esT[c4 * 4 + 1][col] = e.y;
            esT[c4 * 4 + 2][col] = e.z;
            esT[c4 * 4 + 3][col] = e.w;
        }
        __syncthreads();

        float acc[4][4];
        #pragma unroll
        for (int i = 0; i < 4; i++)
            #pragma unroll
            for (int j = 0; j < 4; j++) acc[i][j] = 0.f;

        #pragma unroll 2
        for (int c = 0; c < 64; c += 4) {
            int kgf = ((kg ^ ((c >> 2) & 7)) << 2);
            float4 e0 = *(const float4*)&esT[c + 0][kgf];
            float4 e1 = *(const float4*)&esT[c + 1][kgf];
            float4 e2 = *(const float4*)&esT[c + 2][kgf];
            float4 e3 = *(const float4*)&esT[c + 3][kgf];
            #pragma unroll
            for (int i = 0; i < 4; i++) {
                float4 xt = *(const float4*)&xs[rg * 4 + i][c];
                acc[i][0] += xt.x * e0.x + xt.y * e1.x + xt.z * e2.x + xt.w * e3.x;
                acc[i][1] += xt.x * e0.y + xt.y * e1.y + xt.z * e2.y + xt.w * e3.y;
                acc[i][2] += xt.x * e0.z + xt.y * e1.z + xt.z * e2.z + xt.w * e3.z;
                acc[i][3] += xt.x * e0.w + xt.y * e1.w + xt.z * e2.w + xt.w * e3.w;
            }
        }

        float4 eq = *(const float4*)&esq[k0 + kg * 4];
        #pragma unroll
        for (int i = 0; i < 4; i++) {
            int r = rg * 4 + i;
            float xq = xsq[r];
            float d0v = (xq + eq.x) - 2.f * acc[i][0];
            float d1v = (xq + eq.y) - 2.f * acc[i][1];
            float d2v = (xq + eq.z) - 2.f * acc[i][2];
            float d3v = (xq + eq.w) - 2.f * acc[i][3];
            float4 st; st.x = d0v; st.y = d1v; st.z = d2v; st.w = d3v;
            *(float4*)&d0[(size_t)(n0 + r) * K0 + k0 + kg * 4] = st;
            float p0 = C2E * d0v, p1 = C2E * d1v, p2 = C2E * d2v, p3 = C2E * d3v;
            float mm = fmaxf(fmaxf(p0, p1), fmaxf(p2, p3));
            float Mn = fmaxf(m2r[i], mm);
            float ss = __builtin_amdgcn_exp2f(p0 - Mn) + __builtin_amdgcn_exp2f(p1 - Mn)
                     + __builtin_amdgcn_exp2f(p2 - Mn) + __builtin_amdgcn_exp2f(p3 - Mn);
            sr[i] = sr[i] * __builtin_amdgcn_exp2f(m2r[i] - Mn) + ss;
            m2r[i] = Mn;
        }
        __syncthreads();
    }

    // single cross-lane reduce over the 32 kg lanes
    #pragma unroll
    for (int off = 1; off < 32; off <<= 1) {
        #pragma unroll
        for (int i = 0; i < 4; i++) {
            float m2 = __shfl_xor(m2r[i], off, 64);
            float s2 = __shfl_xor(sr[i], off, 64);
            float Mn = fmaxf(m2r[i], m2);
            sr[i] = sr[i] * __builtin_amdgcn_exp2f(m2r[i] - Mn)
                  + s2 * __builtin_amdgcn_exp2f(m2 - Mn);
            m2r[i] = Mn;
        }
    }
    if (kg == 0) {
        #pragma unroll
        for (int i = 0; i < 4; i++) {
            int r = rg * 4 + i;
            stats[(size_t)(n0 + r) * 2]     = m2r[i];
            stats[(size_t)(n0 + r) * 2 + 1] = sr[i];
        }
    }
}

// ---------------- kernel B: stage-0 prob -> a0, q_feat -> qx0 ----------------
// Baseline 32-row tiling (3 blocks/CU) + register prefetch of next d0 chunk
// + float4 es staging + base-2 exp.
__global__ __launch_bounds__(256) void k_prob0(const float* __restrict__ x0,
                                               const float* __restrict__ cb,
                                               const float* __restrict__ stats,
                                               const int* __restrict__ iter,
                                               const float* __restrict__ d0,
                                               float* __restrict__ out) {
    __shared__ __align__(16) float es[128][68];   // [kk][c]
    __shared__ float ptT[128][33];                // [kk][r]
    __shared__ float rowMv[32], rowIS[32];

    const int t = threadIdx.x;
    const int n0 = blockIdx.x * 32;
    const int b = n0 / HW, hw0 = n0 % HW;

    if (t < 32) {
        rowMv[t] = stats[(size_t)(n0 + t) * 2];
        rowIS[t] = 1.f / stats[(size_t)(n0 + t) * 2 + 1];
    }
    __syncthreads();

    const int r1 = t >> 3;          // 0..31
    const int ks1 = (t & 7) * 16;   // 16-k slice
    const int rq = t & 31;
    const int cg = t >> 5;          // 0..7 -> 8 channels each
    const float Mr1 = rowMv[r1], IS1 = rowIS[r1];

    float qf[8];
    #pragma unroll
    for (int q = 0; q < 8; q++) qf[q] = 0.f;

    float* a0 = out + OFF_A0;

    float4 dpre[4];
    {
        const float* dr = &d0[(size_t)(n0 + r1) * K0 + ks1];
        #pragma unroll
        for (int q = 0; q < 4; q++) dpre[q] = *(const float4*)&dr[q * 4];
    }

    for (int k0 = 0; k0 < K0; k0 += 128) {
        for (int i = t; i < 2048; i += 256) {
            int c4 = i & 15, kk = i >> 4;
            *(float4*)&es[kk][c4 * 4] =
                *(const float4*)&cb[(size_t)(k0 + kk) * C0 + c4 * 4];
        }
        #pragma unroll
        for (int q = 0; q < 4; q++) {
            float4 dv = dpre[q];
            int kb = ks1 + q * 4;
            ptT[kb + 0][r1] = __builtin_amdgcn_exp2f(C2E * dv.x - Mr1) * IS1;
            ptT[kb + 1][r1] = __builtin_amdgcn_exp2f(C2E * dv.y - Mr1) * IS1;
            ptT[kb + 2][r1] = __builtin_amdgcn_exp2f(C2E * dv.z - Mr1) * IS1;
            ptT[kb + 3][r1] = __builtin_amdgcn_exp2f(C2E * dv.w - Mr1) * IS1;
        }
        if (k0 + 128 < K0) {   // prefetch next chunk; hides under a0+qf phases
            const float* dr = &d0[(size_t)(n0 + r1) * K0 + k0 + 128 + ks1];
            #pragma unroll
            for (int q = 0; q < 4; q++) dpre[q] = *(const float4*)&dr[q * 4];
        }
        __syncthreads();
        #pragma unroll
        for (int jj = 0; jj < 16; jj++) {
            int pos = jj * 256 + t;
            int kk = pos >> 5, r = pos & 31;
            a0[(size_t)(b * K0 + k0 + kk) * HW + hw0 + r] = ptT[kk][r];
        }
        #pragma unroll 8
        for (int kk = 0; kk < 128; kk++) {
            float p = ptT[kk][rq];
            float4 e0 = *(const float4*)&es[kk][cg * 8];
            float4 e1 = *(const float4*)&es[kk][cg * 8 + 4];
            qf[0] += p * e0.x; qf[1] += p * e0.y; qf[2] += p * e0.z; qf[3] += p * e0.w;
            qf[4] += p * e1.x; qf[5] += p * e1.y; qf[6] += p * e1.z; qf[7] += p * e1.w;
        }
        __syncthreads();
    }
    float gate = fmaxf((10000.f - (float)(*iter)) / 10000.f, 0.f);
    float om = 1.f - gate;
    #pragma unroll
    for (int q = 0; q < 8; q++) {
        int c = cg * 8 + q;
        size_t idx = (size_t)(b * C0 + c) * HW + hw0 + rq;
        out[OFF_QX0 + idx] = gate * x0[idx] + om * qf[q];
    }
}

// ---------------- kernel C: fused head (two 1x1 convs + relu) ----------------
__global__ __launch_bounds__(256) void k_head(const float* __restrict__ w1,
                                              const float* __restrict__ b1,
                                              const float* __restrict__ w2,
                                              const float* __restrict__ b2,
                                              float* __restrict__ out) {
    __shared__ __align__(16) float xin[32][64];
    __shared__ __align__(16) float y1s[32][256];
    __shared__ __align__(16) float wst[64][68];

    const int t = threadIdx.x;
    const int n0 = blockIdx.x * 32;
    const int b = n0 / HW, hw0 = n0 % HW;
    const float* qx0 = out + OFF_QX0;
    float* x3 = out + OFF_X3;

    for (int i = t; i < 32 * 64; i += 256) {
        int c = i >> 5, r = i & 31;
        xin[r][c] = qx0[(size_t)(b * C0 + c) * HW + hw0 + r];
    }
    __syncthreads();

    const int rg = t >> 5;
    const int og = t & 31;

    for (int op = 0; op < 4; op++) {
        int ob = op * 64;
        for (int i = t; i < 64 * 64; i += 256) {
            int c = i & 63, o = i >> 6;
            wst[c][o] = w1[(size_t)(ob + o) * C0 + c];
        }
        __syncthreads();
        float2 bb = *(const float2*)&b1[ob + og * 2];
        float acc[4][2];
        #pragma unroll
        for (int i = 0; i < 4; i++) { acc[i][0] = bb.x; acc[i][1] = bb.y; }
        #pragma unroll 2
        for (int c = 0; c < 64; c += 4) {
            float xv[4][4];
            #pragma unroll
            for (int i = 0; i < 4; i++) {
                float4 xt = *(const float4*)&xin[rg * 4 + i][c];
                xv[i][0] = xt.x; xv[i][1] = xt.y; xv[i][2] = xt.z; xv[i][3] = xt.w;
            }
            #pragma unroll
            for (int q = 0; q < 4; q++) {
                float2 wv = *(const float2*)&wst[c + q][og * 2];
                #pragma unroll
                for (int i = 0; i < 4; i++) {
                    acc[i][0] += xv[i][q] * wv.x;
                    acc[i][1] += xv[i][q] * wv.y;
                }
            }
        }
        #pragma unroll
        for (int i = 0; i < 4; i++) {
            float2 st;
            st.x = fmaxf(acc[i][0], 0.f);
            st.y = fmaxf(acc[i][1], 0.f);
            *(float2*)&y1s[rg * 4 + i][ob + og * 2] = st;
        }
        __syncthreads();
    }

    for (int p = 0; p < 4; p++) {
        int ob = p * 64;
        float2 bb = *(const float2*)&b2[ob + og * 2];
        float acc[4][2];
        #pragma unroll
        for (int i = 0; i < 4; i++) { acc[i][0] = bb.x; acc[i][1] = bb.y; }
        for (int cc0 = 0; cc0 < 256; cc0 += 64) {
            for (int i = t; i < 64 * 64; i += 256) {
                int c = i & 63, o = i >> 6;
                wst[c][o] = w2[(size_t)(ob + o) * C1 + cc0 + c];
            }
            __syncthreads();
            #pragma unroll 2
            for (int c = 0; c < 64; c += 4) {
                float yv[4][4];
                #pragma unroll
                for (int i = 0; i < 4; i++) {
                    float4 yt = *(const float4*)&y1s[rg * 4 + i][cc0 + c];
                    yv[i][0] = yt.x; yv[i][1] = yt.y; yv[i][2] = yt.z; yv[i][3] = yt.w;
                }
                #pragma unroll
                for (int q = 0; q < 4; q++) {
                    float2 wv = *(const float2*)&wst[c + q][og * 2];
                    #pragma unroll
                    for (int i = 0; i < 4; i++) {
                        acc[i][0] += yv[i][q] * wv.x;
                        acc[i][1] += yv[i][q] * wv.y;
                    }
                }
            }
            __syncthreads();
        }
        #pragma unroll
        for (int i = 0; i < 4; i++)
            *(float2*)&wst[0][0 + (size_t)(rg * 4 + i) * 68 + og * 2] =
                make_float2(acc[i][0], acc[i][1]);
        __syncthreads();
        for (int i = t; i < 32 * 64; i += 256) {
            int o = i >> 5, r = i & 31;
            x3[(size_t)(b * C1 + ob + o) * HW + hw0 + r] = wst[0][(size_t)r * 68 + o];
        }
        __syncthreads();
    }
}

// ---------------- kernel D: stage-1 distances + stats ----------------
// Baseline tiling (4 blocks/CU) + per-thread online stats (no per-chunk shuffles).
__global__ __launch_bounds__(256) void k_dist1(const float* __restrict__ cb,
                                               const float* __restrict__ esq,
                                               const float* __restrict__ x3,
                                               float* __restrict__ d3,
                                               float* __restrict__ stats) {
    __shared__ __align__(16) float xs[32][132];   // c-half staging
    __shared__ float esT[128][33];                // [c'][kk]
    __shared__ float xsq[32];
    __shared__ float part[32][8];

    const int t = threadIdx.x;
    const int n0 = blockIdx.x * 32;
    const int b = n0 / HW, hw0 = n0 % HW;

    {
        int r = t & 31, seg = t >> 5;
        float s = 0.f;
        for (int j = 0; j < 32; j++) {
            float v = x3[(size_t)(b * C1 + seg * 32 + j) * HW + hw0 + r];
            s += v * v;
        }
        part[r][seg] = s;
    }
    __syncthreads();
    if (t < 32) {
        float s = 0.f;
        for (int j = 0; j < 8; j++) s += part[t][j];
        xsq[t] = s;
    }
    __syncthreads();

    const int rg = t >> 5;
    const int kg = t & 31;

    float m2r[4], sr[4];
    #pragma unroll
    for (int i = 0; i < 4; i++) { m2r[i] = -3.0e38f; sr[i] = 0.f; }

    for (int k0 = 0; k0 < K1; k0 += 32) {
        float acc[4] = {0.f, 0.f, 0.f, 0.f};
        for (int ch = 0; ch < 2; ch++) {
            for (int i = t; i < 32 * 128; i += 256) {
                int c = i & 127, kk = i >> 7;
                esT[c][kk] = cb[(size_t)(k0 + kk) * C1 + ch * 128 + c];
            }
            for (int i = t; i < 32 * 128; i += 256) {
                int ci = i >> 5, r = i & 31;
                xs[r][ci] = x3[(size_t)(b * C1 + ch * 128 + ci) * HW + hw0 + r];
            }
            __syncthreads();
            #pragma unroll 2
            for (int c = 0; c < 128; c += 4) {
                float ev[4];
                #pragma unroll
                for (int q = 0; q < 4; q++) ev[q] = esT[c + q][kg];
                #pragma unroll
                for (int i = 0; i < 4; i++) {
                    float4 xt = *(const float4*)&xs[rg * 4 + i][c];
                    acc[i] += xt.x * ev[0] + xt.y * ev[1] + xt.z * ev[2] + xt.w * ev[3];
                }
            }
            __syncthreads();
        }
        float eqv = esq[k0 + kg];
        #pragma unroll
        for (int i = 0; i < 4; i++) {
            int r = rg * 4 + i;
            float dv = (xsq[r] + eqv) - 2.f * acc[i];
            d3[(size_t)(n0 + r) * K1 + k0 + kg] = dv;
            float p = C2E * dv;
            float Mn = fmaxf(m2r[i], p);
            sr[i] = sr[i] * __builtin_amdgcn_exp2f(m2r[i] - Mn)
                  + __builtin_amdgcn_exp2f(p - Mn);
            m2r[i] = Mn;
        }
    }

    #pragma unroll
    for (int off = 1; off < 32; off <<= 1) {
        #pragma unroll
        for (int i = 0; i < 4; i++) {
            float m2 = __shfl_xor(m2r[i], off, 64);
            float s2 = __shfl_xor(sr[i], off, 64);
            float Mn = fmaxf(m2r[i], m2);
            sr[i] = sr[i] * __builtin_amdgcn_exp2f(m2r[i] - Mn)
                  + s2 * __builtin_amdgcn_exp2f(m2 - Mn);
            m2r[i] = Mn;
        }
    }
    if (kg == 0) {
        #pragma unroll
        for (int i = 0; i < 4; i++) {
            int r = rg * 4 + i;
            stats[(size_t)(n0 + r) * 2]     = m2r[i];
            stats[(size_t)(n0 + r) * 2 + 1] = sr[i];
        }
    }
}

// ---------------- kernel E: stage-1 prob -> a3, q_feat -> qx3 ----------------
// Baseline tiling + d3 prefetch + float4 es staging + base-2 exp.
__global__ __launch_bounds__(256) void k_prob1(const float* __restrict__ cb,
                                               const float* __restrict__ stats,
                                               const int* __restrict__ iter,
                                               const float* __restrict__ d3,
                                               float* __restrict__ out) {
    __shared__ __align__(16) float es[64][132];   // [kk][c-half]
    __shared__ float ptT[64][33];
    __shared__ float rowMv[32], rowIS[32];

    const int t = threadIdx.x;
    const int n0 = blockIdx.x * 32;
    const int b = n0 / HW, hw0 = n0 % HW;

    if (t < 32) {
        rowMv[t] = stats[(size_t)(n0 + t) * 2];
        rowIS[t] = 1.f / stats[(size_t)(n0 + t) * 2 + 1];
    }
    __syncthreads();

    const int r1 = t >> 3;
    const int ks1 = (t & 7) * 8;
    const int rq = t & 31;
    const int cg = t >> 5;
    const float Mr1 = rowMv[r1], IS1 = rowIS[r1];

    float qf0[16], qf1[16];
    #pragma unroll
    for (int q = 0; q < 16; q++) { qf0[q] = 0.f; qf1[q] = 0.f; }

    const float* x3 = out + OFF_X3;
    float* a3 = out + OFF_A3;

    float4 dpre0, dpre1;
    {
        const float* dr = &d3[(size_t)(n0 + r1) * K1 + ks1];
        dpre0 = *(const float4*)&dr[0];
        dpre1 = *(const float4*)&dr[4];
    }

    for (int k0 = 0; k0 < K1; k0 += 64) {
        {
            float4 v0 = dpre0, v1 = dpre1;
            ptT[ks1 + 0][r1] = __builtin_amdgcn_exp2f(C2E * v0.x - Mr1) * IS1;
            ptT[ks1 + 1][r1] = __builtin_amdgcn_exp2f(C2E * v0.y - Mr1) * IS1;
            ptT[ks1 + 2][r1] = __builtin_amdgcn_exp2f(C2E * v0.z - Mr1) * IS1;
            ptT[ks1 + 3][r1] = __builtin_amdgcn_exp2f(C2E * v0.w - Mr1) * IS1;
            ptT[ks1 + 4][r1] = __builtin_amdgcn_exp2f(C2E * v1.x - Mr1) * IS1;
            ptT[ks1 + 5][r1] = __builtin_amdgcn_exp2f(C2E * v1.y - Mr1) * IS1;
            ptT[ks1 + 6][r1] = __builtin_amdgcn_exp2f(C2E * v1.z - Mr1) * IS1;
            ptT[ks1 + 7][r1] = __builtin_amdgcn_exp2f(C2E * v1.w - Mr1) * IS1;
        }
        if (k0 + 64 < K1) {
            const float* dr = &d3[(size_t)(n0 + r1) * K1 + k0 + 64 + ks1];
            dpre0 = *(const float4*)&dr[0];
            dpre1 = *(const float4*)&dr[4];
        }
        for (int i = t; i < 2048; i += 256) {     // es half0 (c 0..127)
            int c4 = i & 31, kk = i >> 5;
            *(float4*)&es[kk][c4 * 4] =
                *(const float4*)&cb[(size_t)(k0 + kk) * C1 + c4 * 4];
        }
        __syncthreads();
        #pragma unroll
        for (int jj = 0; jj < 8; jj++) {
            int pos = jj * 256 + t;
            int kk = pos >> 5, r = pos & 31;
            a3[(size_t)(b * K1 + k0 + kk) * HW + hw0 + r] = ptT[kk][r];
        }
        #pragma unroll 4
        for (int kk = 0; kk < 64; kk++) {
            float p = ptT[kk][rq];
            #pragma unroll
            for (int q = 0; q < 4; q++) {
                float4 e = *(const float4*)&es[kk][cg * 16 + q * 4];
                qf0[q * 4 + 0] += p * e.x;
                qf0[q * 4 + 1] += p * e.y;
                qf0[q * 4 + 2] += p * e.z;
                qf0[q * 4 + 3] += p * e.w;
            }
        }
        __syncthreads();
        for (int i = t; i < 2048; i += 256) {     // es half1 (c 128..255)
            int c4 = i & 31, kk = i >> 5;
            *(float4*)&es[kk][c4 * 4] =
                *(const float4*)&cb[(size_t)(k0 + kk) * C1 + 128 + c4 * 4];
        }
        __syncthreads();
        #pragma unroll 4
        for (int kk = 0; kk < 64; kk++) {
            float p = ptT[kk][rq];
            #pragma unroll
            for (int q = 0; q < 4; q++) {
                float4 e = *(const float4*)&es[kk][cg * 16 + q * 4];
                qf1[q * 4 + 0] += p * e.x;
                qf1[q * 4 + 1] += p * e.y;
                qf1[q * 4 + 2] += p * e.z;
                qf1[q * 4 + 3] += p * e.w;
            }
        }
        __syncthreads();
    }
    float gate = fmaxf((10000.f - (float)(*iter)) / 10000.f, 0.f);
    float om = 1.f - gate;
    #pragma unroll
    for (int q = 0; q < 16; q++) {
        int c = cg * 16 + q;
        size_t idx = (size_t)(b * C1 + c) * HW + hw0 + rq;
        out[OFF_QX3 + idx] = gate * x3[idx] + om * qf0[q];
    }
    #pragma unroll
    for (int q = 0; q < 16; q++) {
        int c = 128 + cg * 16 + q;
        size_t idx = (size_t)(b * C1 + c) * HW + hw0 + rq;
        out[OFF_QX3 + idx] = gate * x3[idx] + om * qf1[q];
    }
}

extern "C" void kernel_launch(void* const* d_in, const int* in_sizes, int n_in,
                              void* d_out, int out_size, void* d_ws, size_t ws_size,
                              hipStream_t stream) {
    (void)in_sizes; (void)n_in; (void)out_size; (void)ws_size;
    const float* x0  = (const float*)d_in[0];
    const float* vq0 = (const float*)d_in[1];
    const float* vq1 = (const float*)d_in[2];
    const float* w1  = (const float*)d_in[3];
    const float* b1  = (const float*)d_in[4];
    const float* w2  = (const float*)d_in[5];
    const float* b2  = (const float*)d_in[6];
    const int*   it  = (const int*)d_in[7];
    float* out = (float*)d_out;
    float* ws  = (float*)d_ws;
    float* esq0   = ws;                        // 2048
    float* esq1   = ws + 2048;                 // 512
    float* stats0 = ws + 2560;                 // 2*51200
    float* stats1 = ws + 2560 + 2 * 51200;     // 2*51200

    hipLaunchKernelGGL(k_esq,   dim3(10),   dim3(256), 0, stream, vq0, vq1, ws);
    hipLaunchKernelGGL(k_dist0, dim3(1600), dim3(256), 0, stream, x0, vq0, esq0,
                       out + OFF_D0, stats0);
    hipLaunchKernelGGL(k_prob0, dim3(1600), dim3(256), 0, stream, x0, vq0, stats0, it,
                       out + OFF_D0, out);
    hipLaunchKernelGGL(k_head,  dim3(1600), dim3(256), 0, stream, w1, b1, w2, b2, out);
    hipLaunchKernelGGL(k_dist1, dim3(1600), dim3(256), 0, stream, vq1, esq1,
                       out + OFF_X3, out + OFF_D3, stats1);
    hipLaunchKernelGGL(k_prob1, dim3(1600), dim3(256), 0, stream, vq1, stats1, it,
                       out + OFF_D3, out);
}